// Round 10
// baseline (165.896 us; speedup 1.0000x reference)
//
#include <hip/hip_runtime.h>

#define N_NODES  50000
#define N_EDGES  1600000
#define N_FEAT   50
#define HID      20
#define OUT_DIM  10
#define N_GRAPHS 64

#define NBUCK 250            // buckets of exactly 200 nodes (50000/200)
#define NPB   200            // nodes per bucket
#define BCAP  8192           // padded slots/bucket (avg 6400, +22 sigma)
#define EPB   6250           // edges per scatter chunk (N_EDGES/256)
#define YSTR  32             // bf16 elems per y row -> 64B, one cache line
#define OPB   3907           // gemm50 outputs per block (ceil(1e6/256))
#define NBLK  256

__device__ __forceinline__ unsigned short f2bf(float f) {
    unsigned int u = __float_as_uint(f);
    u += 0x7FFFu + ((u >> 16) & 1u);          // round-to-nearest-even
    return (unsigned short)(u >> 16);
}
__device__ __forceinline__ unsigned int pk2(float f0, float f1) {
    return (unsigned int)f2bf(f0) | ((unsigned int)f2bf(f1) << 16);
}
__device__ __forceinline__ float blo(unsigned int u) { return __uint_as_float(u << 16); }
__device__ __forceinline__ float bhi(unsigned int u) { return __uint_as_float(u & 0xFFFF0000u); }
// exact d/200 for d < 199729 (error bound: 168*d < 2^25)
__device__ __forceinline__ int dkey(unsigned int d) {
    return (int)(((unsigned long long)d * 167773ull) >> 25);
}
// add one bf16 message row (20 vals, one 64B line) into 20 f32 registers
__device__ __forceinline__ void addrow(const unsigned short* __restrict__ yb,
                                       int sn, float* a) {
    const unsigned short* p = yb + (size_t)sn * YSTR;
    uint4 q0 = *(const uint4*)(p);
    uint4 q1 = *(const uint4*)(p + 8);
    uint2 q2 = *(const uint2*)(p + 16);
    a[0] += blo(q0.x); a[1] += bhi(q0.x); a[2] += blo(q0.y); a[3] += bhi(q0.y);
    a[4] += blo(q0.z); a[5] += bhi(q0.z); a[6] += blo(q0.w); a[7] += bhi(q0.w);
    a[8] += blo(q1.x); a[9] += bhi(q1.x); a[10] += blo(q1.y); a[11] += bhi(q1.y);
    a[12] += blo(q1.z); a[13] += bhi(q1.z); a[14] += blo(q1.w); a[15] += bhi(q1.w);
    a[16] += blo(q2.x); a[17] += bhi(q2.x); a[18] += blo(q2.y); a[19] += bhi(q2.y);
}

__device__ __forceinline__ void gridbar(int* ctr) {
    __syncthreads();                      // waits all block mem ops (vmcnt drain)
    if (threadIdx.x == 0) {
        __threadfence();                  // release: flush to device-visible point
        atomicAdd(ctr, 1);
        while (atomicAdd(ctr, 0) < NBLK) __builtin_amdgcn_s_sleep(2);
        __threadfence();                  // acquire: invalidate L1/L2
    }
    __syncthreads();
}

// register-gather over the LDS-resident sorted edge list, staged combine into BUF
#define GATHER(YIN, BUF)                                                          \
    {                                                                             \
        int slot_ = t / 5, q_ = t - slot_ * 5;                                    \
        float a_[HID];                                                            \
        _Pragma("unroll")                                                         \
        for (int j_ = 0; j_ < HID; ++j_) a_[j_] = 0.f;                            \
        int nl_ = 0;                                                              \
        if (slot_ < NPB) {                                                        \
            nl_ = sperm[slot_];                                                   \
            int cb_ = sstart[nl_], ce_ = cb_ + scnt[nl_];                         \
            _Pragma("unroll 2")                                                   \
            for (int k_ = cb_ + q_; k_ < ce_; k_ += 5) addrow(YIN, eo[k_], a_);   \
        }                                                                         \
        for (int s_ = 0; s_ < 5; ++s_) {                                          \
            if (slot_ < NPB && q_ == s_) {                                        \
                _Pragma("unroll")                                                 \
                for (int qq_ = 0; qq_ < 5; ++qq_) {                               \
                    float4* p_ = (float4*)&BUF[nl_ * HID + qq_ * 4];              \
                    float4 v_ = *p_;                                              \
                    v_.x += a_[qq_*4];   v_.y += a_[qq_*4+1];                     \
                    v_.z += a_[qq_*4+2]; v_.w += a_[qq_*4+3];                     \
                    *p_ = v_;                                                     \
                }                                                                 \
            }                                                                     \
            __syncthreads();                                                      \
        }                                                                         \
    }

// 20x20 dual GEMM from LDS BIN: y (bf16, global) + next acc (LDS AOUT)
#define GEMMX(BIN, YOUT, AOUT)                                                    \
    {                                                                             \
        for (int i_ = t; i_ < NPB * 5; i_ += 1024) {                              \
            int n_ = i_ / 5, j0_ = (i_ - n_ * 5) * 4;                             \
            float y0_=0.f, y1_=0.f, y2_=0.f, y3_=0.f;                             \
            float c0_=wbuf[800+j0_], c1_=wbuf[801+j0_],                           \
                  c2_=wbuf[802+j0_], c3_=wbuf[803+j0_];                           \
            _Pragma("unroll")                                                     \
            for (int k_ = 0; k_ < HID; ++k_) {                                    \
                float h_ = fmaxf(BIN[n_ * HID + k_], 0.f);                        \
                const float* wr_ = wbuf + k_ * HID + j0_;                         \
                const float* wo_ = wbuf + 400 + k_ * HID + j0_;                   \
                y0_=fmaf(h_,wr_[0],y0_); y1_=fmaf(h_,wr_[1],y1_);                 \
                y2_=fmaf(h_,wr_[2],y2_); y3_=fmaf(h_,wr_[3],y3_);                 \
                c0_=fmaf(h_,wo_[0],c0_); c1_=fmaf(h_,wo_[1],c1_);                 \
                c2_=fmaf(h_,wo_[2],c2_); c3_=fmaf(h_,wo_[3],c3_);                 \
            }                                                                     \
            *(uint2*)(YOUT + (size_t)(n0 + n_) * YSTR + j0_) =                    \
                make_uint2(pk2(y0_, y1_), pk2(y2_, y3_));                         \
            *(float4*)&AOUT[n_ * HID + j0_] = make_float4(c0_, c1_, c2_, c3_);    \
        }                                                                         \
        __syncthreads();                                                          \
    }

__global__ __launch_bounds__(1024) void mega(
        const int* __restrict__ dst, const int* __restrict__ srcv,
        const float* __restrict__ x, const int* __restrict__ batch,
        const float* __restrict__ Wrel1, const float* __restrict__ Wroot1,
        const float* __restrict__ b1,
        const float* __restrict__ Wrel2, const float* __restrict__ Wroot2,
        const float* __restrict__ b2,
        const float* __restrict__ Wrel3, const float* __restrict__ Wroot3,
        const float* __restrict__ b3,
        const float* __restrict__ Wlin, const float* __restrict__ blin,
        unsigned short* __restrict__ yA, unsigned short* __restrict__ yB,
        float* __restrict__ acc1, unsigned int* __restrict__ padded,
        int* __restrict__ gcur, int* __restrict__ bar, int* __restrict__ done,
        float* __restrict__ gmax, float* __restrict__ gsum, float* __restrict__ gcnt,
        float* __restrict__ out) {
    // LDS layout (61952 B):
    // [0,16384)      eo: sorted src lists (persists ph1-3) / scatter rnk (ph0)
    // [16384,32768)  bufA: sort rnk (ph1) -> acc accum A ; with bufB = scatter ep2 (ph0)
    // [32768,49152)  bufB: acc accum B / redm+reds (ph3)
    // [49152,57344)  wbuf: weights (8KB ph0; 3.3KB ph1+)
    // [57344,58368)  sstart / lofs      [58368,59392) scnt / gbase
    // [59392,60416)  cnt / sbatch       [60416,61440) scn / seg
    // [61440,61952)  sperm
    __shared__ char smem[61952];
    unsigned short* eo     = (unsigned short*)smem;
    float*          bufA   = (float*)(smem + 16384);
    float*          bufB   = (float*)(smem + 32768);
    float*          wbuf   = (float*)(smem + 49152);
    int*            sstart = (int*)(smem + 57344);
    int*            scnt   = (int*)(smem + 58368);
    int*            cnt    = (int*)(smem + 59392);
    int*            scn    = (int*)(smem + 60416);
    unsigned short* sperm  = (unsigned short*)(smem + 61440);
    __shared__ int lastFlag;

    int bid = blockIdx.x, t = threadIdx.x;

    // ================= PHASE 0: gemm50 slice + edge scatter =================
    for (int i = t; i < N_FEAT * HID; i += 1024) {
        wbuf[i] = Wrel1[i];
        wbuf[1000 + i] = Wroot1[i];
    }
    if (bid == 0) {
        for (int i = t; i < N_GRAPHS * HID; i += 1024) { gmax[i] = 0.f; gsum[i] = 0.f; }
        if (t < N_GRAPHS) gcnt[t] = 0.f;
    }
    __syncthreads();
    {
        int i1 = min(bid * OPB + OPB, N_NODES * HID);
        for (int idx = bid * OPB + t; idx < i1; idx += 1024) {
            int n = idx / HID, j = idx - n * HID;
            const float* xr = x + n * N_FEAT;
            float a0 = 0.f, a1 = b1[j];
            #pragma unroll
            for (int k = 0; k < N_FEAT; ++k) {
                float xv = xr[k];
                a0 = fmaf(xv, wbuf[k * HID + j], a0);
                a1 = fmaf(xv, wbuf[1000 + k * HID + j], a1);
            }
            yA[(size_t)n * YSTR + j] = f2bf(a0);
            acc1[idx] = a1;
        }
    }
    __syncthreads();
    {   // scatter chunk bid: rank trick (1 LDS atomic/edge) + coalesced write
        unsigned short* rnk = eo;                       // 12500 B
        unsigned int* ep2 = (unsigned int*)bufA;        // 25000 B (bufA+bufB)
        int* lofs = sstart; int* gbase = scnt;
        if (t < 256) cnt[t] = 0;
        __syncthreads();
        int e0 = bid * EPB;
        for (int i = t; i < EPB; i += 1024) {
            unsigned int d = (unsigned int)dst[e0 + i];
            rnk[i] = (unsigned short)atomicAdd(&cnt[dkey(d)], 1);
        }
        __syncthreads();
        if (t < 256) scn[t] = cnt[t];
        __syncthreads();
        for (int d2 = 1; d2 < 256; d2 <<= 1) {
            int u = 0;
            if (t < 256 && t >= d2) u = scn[t - d2];
            __syncthreads();
            if (t < 256) scn[t] += u;
            __syncthreads();
        }
        if (t < 256) lofs[t] = scn[t] - cnt[t];
        if (t < NBUCK) gbase[t] = t * BCAP + atomicAdd(&gcur[t], cnt[t]);
        __syncthreads();
        for (int i = t; i < EPB; i += 1024) {
            unsigned int d = (unsigned int)dst[e0 + i];
            unsigned int s = (unsigned int)srcv[e0 + i];
            ep2[lofs[dkey(d)] + rnk[i]] = (d << 16) | s;
        }
        __syncthreads();
        for (int i = t; i < EPB; i += 1024) {
            unsigned int e = ep2[i];
            int key = dkey(e >> 16);
            int gp = gbase[key] + (i - lofs[key]);
            if (gp < (key + 1) * BCAP) padded[gp] = e;  // guard never fires
        }
    }
    gridbar(&bar[0]);

    // ====== PHASE 1: per-bucket counting sort (LDS) + perm + gather1 + gemm2 ======
    if (bid < NBUCK) {
        int base = bid * BCAP;
        int m = min(gcur[bid], BCAP);
        int n0 = bid * NPB;
        for (int i = t; i < HID * HID; i += 1024) { wbuf[i] = Wrel2[i]; wbuf[400 + i] = Wroot2[i]; }
        if (t < HID) wbuf[800 + t] = b2[t];
        unsigned short* rnk = (unsigned short*)bufA;    // 16384 B exact
        if (t < 256) cnt[t] = 0;
        __syncthreads();
        for (int i = t; i < m; i += 1024) {
            int local = (int)(padded[base + i] >> 16) - n0;
            rnk[i] = (unsigned short)atomicAdd(&cnt[local], 1);
        }
        __syncthreads();
        if (t < 256) scn[t] = cnt[t];
        __syncthreads();
        for (int d2 = 1; d2 < 256; d2 <<= 1) {
            int u = 0;
            if (t < 256 && t >= d2) u = scn[t - d2];
            __syncthreads();
            if (t < 256) scn[t] += u;
            __syncthreads();
        }
        if (t < 256) { sstart[t] = scn[t] - cnt[t]; scnt[t] = cnt[t]; }
        __syncthreads();
        for (int i = t; i < m; i += 1024) {
            unsigned int e = padded[base + i];
            int local = (int)(e >> 16) - n0;
            eo[sstart[local] + rnk[i]] = (unsigned short)(e & 0xFFFFu);
        }
        __syncthreads();                                 // rnk dead
        // degree-descending perm (comparison rank, no atomics)
        if (t < 256) {
            int d = scnt[t], rank = 0;
            for (int j2 = 0; j2 < 256; ++j2) {
                int dj = scnt[j2];
                rank += (dj > d) || (dj == d && j2 < t);
            }
            sperm[rank] = (unsigned short)t;
        }
        // root term of layer 1 into bufA (overwrites rnk)
        __syncthreads();
        for (int i = t; i < NPB * HID; i += 1024) bufA[i] = acc1[n0 * HID + i];
        __syncthreads();
        GATHER(yA, bufA)
        GEMMX(bufA, yB, bufB)
    }
    gridbar(&bar[1]);

    // ================= PHASE 2: gather2 + gemm3 =================
    if (bid < NBUCK) {
        int n0 = bid * NPB;
        for (int i = t; i < HID * HID; i += 1024) { wbuf[i] = Wrel3[i]; wbuf[400 + i] = Wroot3[i]; }
        if (t < HID) wbuf[800 + t] = b3[t];
        GATHER(yB, bufB)
        GEMMX(bufB, yA, bufA)
    }
    gridbar(&bar[2]);

    // ================= PHASE 3: gather3 + pooling =================
    if (bid < NBUCK) {
        int n0 = bid * NPB;
        GATHER(yA, bufA)
        int* sbatch = cnt;        // int[200]
        int* seg = scn;           // seglo [0..15], seghi [16..31]
        if (t < NPB) sbatch[t] = batch[n0 + t];
        __syncthreads();
        int g0 = sbatch[0];
        int span = sbatch[NPB - 1] - g0 + 1;
        if (t < NPB) {
            int bi = sbatch[t] - g0;
            if (bi < 16) {
                if (t == 0 || sbatch[t - 1] != sbatch[t]) seg[bi] = t;
                if (t == NPB - 1 || sbatch[t + 1] != sbatch[t]) seg[16 + bi] = t + 1;
            }
        }
        __syncthreads();
        if (span > 16) span = 16;
        float* redm = bufB;            // 1020 floats
        float* reds = bufB + 1020;     // 1020 floats
        for (int li = 0; li < span; ++li) {
            int lo = seg[li], hi = seg[16 + li];
            int r = t / HID, j = t - r * HID;
            if (r < 51) {
                float mx = 0.f, sm = 0.f;
                for (int n = lo + r; n < hi; n += 51) {
                    float v = fmaxf(bufA[n * HID + j], 0.f);
                    mx = fmaxf(mx, v); sm += v;
                }
                redm[r * HID + j] = mx; reds[r * HID + j] = sm;
            }
            __syncthreads();
            if (t < HID) {
                float mm = 0.f, ss = 0.f;
                #pragma unroll 17
                for (int r2 = 0; r2 < 51; ++r2) {
                    mm = fmaxf(mm, redm[r2 * HID + t]);
                    ss += reds[r2 * HID + t];
                }
                atomicMax((int*)&gmax[(g0 + li) * HID + t], __float_as_int(mm));
                atomicAdd(&gsum[(g0 + li) * HID + t], ss);
            }
            if (t == HID) atomicAdd(&gcnt[g0 + li], (float)(hi - lo));
            __syncthreads();
        }
    }
    // ================= last block: final linear =================
    if (t == 0) {
        __threadfence();
        lastFlag = (atomicAdd(done, 1) == NBLK - 1);
    }
    __syncthreads();
    if (!lastFlag) return;
    __threadfence();
    float* sW = wbuf;
    for (int i = t; i < 2 * HID * OUT_DIM; i += 1024) sW[i] = Wlin[i];
    __syncthreads();
    if (t < N_GRAPHS * OUT_DIM) {
        int gg = t / OUT_DIM, o = t - gg * OUT_DIM;
        float c = fmaxf(gcnt[gg], 1.0f);
        float av = blin[o];
        #pragma unroll
        for (int j = 0; j < HID; ++j) {
            av = fmaf(gmax[gg * HID + j], sW[j * OUT_DIM + o], av);
            av = fmaf(gsum[gg * HID + j] / c, sW[(HID + j) * OUT_DIM + o], av);
        }
        out[t] = av;
    }
}

extern "C" void kernel_launch(void* const* d_in, const int* in_sizes, int n_in,
                              void* d_out, int out_size, void* d_ws, size_t ws_size,
                              hipStream_t stream) {
    const float* x      = (const float*)d_in[0];
    const int*   ei     = (const int*)  d_in[1];
    const int*   batch  = (const int*)  d_in[2];
    const float* Wrel1  = (const float*)d_in[3];
    const float* Wroot1 = (const float*)d_in[4];
    const float* b1     = (const float*)d_in[5];
    const float* Wrel2  = (const float*)d_in[6];
    const float* Wroot2 = (const float*)d_in[7];
    const float* b2     = (const float*)d_in[8];
    const float* Wrel3  = (const float*)d_in[9];
    const float* Wroot3 = (const float*)d_in[10];
    const float* b3     = (const float*)d_in[11];
    const float* Wlin   = (const float*)d_in[12];
    const float* blin   = (const float*)d_in[13];
    float* out = (float*)d_out;

    char* ws = (char*)d_ws;
    unsigned short* yA     = (unsigned short*)(ws);                    // 3,200,000
    unsigned short* yB     = (unsigned short*)(ws + 3200000);          // 3,200,000
    float*          acc1   = (float*)(ws + 6400000);                   // 4,000,000
    unsigned int*   padded = (unsigned int*)(ws + 10400000);           // 8,192,000
    int*            ctrl   = (int*)(ws + 18592000);                    // gcur[250]+bar[4]+done
    int*            gcur   = ctrl;
    int*            bar    = ctrl + NBUCK;
    int*            done   = ctrl + NBUCK + 4;
    float*          gmax   = (float*)(ws + 18593024);
    float*          gsum   = gmax + N_GRAPHS * HID;
    float*          gcnt   = gsum + N_GRAPHS * HID;

    const int* src = ei;
    const int* dst = ei + N_EDGES;

    // zero bucket counters + barrier counters + done (per launch, graph-safe)
    hipMemsetAsync(ctrl, 0, 1024, stream);
    mega<<<NBLK, 1024, 0, stream>>>(dst, src, x, batch,
                                    Wrel1, Wroot1, b1, Wrel2, Wroot2, b2,
                                    Wrel3, Wroot3, b3, Wlin, blin,
                                    yA, yB, acc1, padded,
                                    gcur, bar, done, gmax, gsum, gcnt, out);
}

// Round 12
// 127.604 us; speedup vs baseline: 1.3001x; 1.3001x over previous
//
#include <hip/hip_runtime.h>

#define N_NODES  50000
#define N_EDGES  1600000
#define N_FEAT   50
#define HID      20
#define OUT_DIM  10
#define N_GRAPHS 64

#define NBUCK 250            // buckets of exactly 200 nodes
#define NPB   200            // nodes per bucket (K2)
#define BCAP  8192           // padded slots/bucket (avg 6400, +22 sigma)
#define EPB   6250           // edges per scatter chunk (N_EDGES/256)
#define YSTR  32             // bf16 elems per y row -> 64B, one cache line
#define GEMMB 977            // ceil(N_NODES*HID/1024)
#define NPB3  100            // nodes per block in K3/K4
#define NBLK3 500            // N_NODES / NPB3

__device__ __forceinline__ unsigned short f2bf(float f) {
    unsigned int u = __float_as_uint(f);
    u += 0x7FFFu + ((u >> 16) & 1u);          // round-to-nearest-even
    return (unsigned short)(u >> 16);
}
__device__ __forceinline__ unsigned int pk2(float f0, float f1) {
    return (unsigned int)f2bf(f0) | ((unsigned int)f2bf(f1) << 16);
}
__device__ __forceinline__ float blo(unsigned int u) { return __uint_as_float(u << 16); }
__device__ __forceinline__ float bhi(unsigned int u) { return __uint_as_float(u & 0xFFFF0000u); }
// exact floor(d/200) for d < 199729
__device__ __forceinline__ int dkey(unsigned int d) {
    return (int)(((unsigned long long)d * 167773ull) >> 25);
}
// add one bf16 message row (20 vals, one 64B line) into 20 f32 registers
__device__ __forceinline__ void addrow(const unsigned short* __restrict__ yb,
                                       int sn, float* a) {
    const unsigned short* p = yb + (size_t)sn * YSTR;
    uint4 q0 = *(const uint4*)(p);
    uint4 q1 = *(const uint4*)(p + 8);
    uint2 q2 = *(const uint2*)(p + 16);
    a[0] += blo(q0.x); a[1] += bhi(q0.x); a[2] += blo(q0.y); a[3] += bhi(q0.y);
    a[4] += blo(q0.z); a[5] += bhi(q0.z); a[6] += blo(q0.w); a[7] += bhi(q0.w);
    a[8] += blo(q1.x); a[9] += bhi(q1.x); a[10] += blo(q1.y); a[11] += bhi(q1.y);
    a[12] += blo(q1.z); a[13] += bhi(q1.z); a[14] += blo(q1.w); a[15] += bhi(q1.w);
    a[16] += blo(q2.x); a[17] += bhi(q2.x); a[18] += blo(q2.y); a[19] += bhi(q2.y);
}

// ================= K1: bucket scatter (rank trick, coalesced) || gemm50 =============

__global__ __launch_bounds__(1024) void k1_scatter_gemm(
        const int* __restrict__ dst, const int* __restrict__ srcv,
        int* __restrict__ gcur, unsigned int* __restrict__ padded,
        const float* __restrict__ x, const float* __restrict__ Wrel,
        const float* __restrict__ Wroot, const float* __restrict__ bb,
        unsigned short* __restrict__ y, float* __restrict__ acc,
        float* __restrict__ gmax, float* __restrict__ gsum, float* __restrict__ gcnt) {
    __shared__ char smem[41728];
    int t = threadIdx.x;
    if (blockIdx.x < 256) {
        unsigned short* rnk = (unsigned short*)smem;           // 12500 B
        unsigned int*   ep2 = (unsigned int*)(smem + 12544);   // 25000 B
        int* cnt   = (int*)(smem + 37632);
        int* scn   = cnt + 256;
        int* lofs  = scn + 256;
        int* gbase = lofs + 256;
        if (blockIdx.x == 0) {
            for (int i = t; i < N_GRAPHS * HID; i += 1024) { gmax[i] = 0.f; gsum[i] = 0.f; }
            if (t < N_GRAPHS) gcnt[t] = 0.f;
        }
        if (t < 256) cnt[t] = 0;
        __syncthreads();
        int e0 = blockIdx.x * EPB;
        for (int i = t; i < EPB; i += 1024) {
            unsigned int d = (unsigned int)dst[e0 + i];
            rnk[i] = (unsigned short)atomicAdd(&cnt[dkey(d)], 1);
        }
        __syncthreads();
        if (t < 256) scn[t] = cnt[t];
        __syncthreads();
        for (int d2 = 1; d2 < 256; d2 <<= 1) {
            int u = 0;
            if (t < 256 && t >= d2) u = scn[t - d2];
            __syncthreads();
            if (t < 256) scn[t] += u;
            __syncthreads();
        }
        if (t < 256) lofs[t] = scn[t] - cnt[t];
        if (t < NBUCK) gbase[t] = t * BCAP + atomicAdd(&gcur[t], cnt[t]);
        __syncthreads();
        for (int i = t; i < EPB; i += 1024) {
            unsigned int d = (unsigned int)dst[e0 + i];
            unsigned int s = (unsigned int)srcv[e0 + i];
            ep2[lofs[dkey(d)] + rnk[i]] = (d << 16) | s;
        }
        __syncthreads();
        for (int i = t; i < EPB; i += 1024) {
            unsigned int e = ep2[i];
            int key = dkey(e >> 16);
            int gp = gbase[key] + (i - lofs[key]);
            if (gp < (key + 1) * BCAP) padded[gp] = e;  // guard never fires
        }
    } else {
        float* sWrel  = (float*)smem;
        float* sWroot = sWrel + N_FEAT * HID;
        for (int i = t; i < N_FEAT * HID; i += 1024) { sWrel[i] = Wrel[i]; sWroot[i] = Wroot[i]; }
        __syncthreads();
        int idx = (blockIdx.x - 256) * 1024 + t;
        if (idx < N_NODES * HID) {
            int n = idx / HID, j = idx % HID;
            const float* xr = x + n * N_FEAT;
            float a0 = 0.f, a1 = bb[j];
            #pragma unroll
            for (int k = 0; k < N_FEAT; ++k) {
                float xv = xr[k];
                a0 = fmaf(xv, sWrel[k * HID + j], a0);
                a1 = fmaf(xv, sWroot[k * HID + j], a1);
            }
            y[(size_t)n * YSTR + j] = f2bf(a0);
            acc[idx] = a1;
        }
    }
}

// ================= K2: counting sort + perm + gather1 (4 lanes/node) + gemm2 ========

__global__ __launch_bounds__(1024) void k2_build_gather(
        const int* __restrict__ gcur, const unsigned int* __restrict__ padded,
        unsigned short* __restrict__ csr16, int* __restrict__ startg,
        int* __restrict__ cntg,
        const unsigned short* __restrict__ y_in, const float* __restrict__ accp,
        const float* __restrict__ Wrel, const float* __restrict__ Wroot,
        const float* __restrict__ bb,
        unsigned short* __restrict__ y_out, float* __restrict__ acc_out) {
    __shared__ unsigned short eo[BCAP];          // 16384 B sorted src lists
    __shared__ char uni[16384];                  // rnk (sort) then rh (gather)
    __shared__ float rh2[NPB * HID];             // 16000 B
    __shared__ float sWrel[HID * HID], sWroot[HID * HID], sb[HID];
    __shared__ int cnt[256], scn[256], sstart[256], scnt[256];
    __shared__ unsigned short sperm[256];
    unsigned short* rnk = (unsigned short*)uni;
    float*          rh  = (float*)uni;
    int g = blockIdx.x, t = threadIdx.x;
    int base = g * BCAP;
    int m = min(gcur[g], BCAP);
    int n0 = g * NPB;
    for (int i = t; i < HID * HID; i += 1024) { sWrel[i] = Wrel[i]; sWroot[i] = Wroot[i]; }
    if (t < HID) sb[t] = bb[t];
    if (t < 256) cnt[t] = 0;
    __syncthreads();
    // pass 1: rank within node (1 LDS atomic/edge)
    for (int i = t; i < m; i += 1024) {
        int local = (int)(padded[base + i] >> 16) - n0;
        rnk[i] = (unsigned short)atomicAdd(&cnt[local], 1);
    }
    __syncthreads();
    if (t < 256) scn[t] = cnt[t];
    __syncthreads();
    for (int d2 = 1; d2 < 256; d2 <<= 1) {
        int u = 0;
        if (t < 256 && t >= d2) u = scn[t - d2];
        __syncthreads();
        if (t < 256) scn[t] += u;
        __syncthreads();
    }
    if (t < 256) {
        sstart[t] = scn[t] - cnt[t];
        scnt[t] = cnt[t];
        if (t < NPB) { startg[n0 + t] = base + sstart[t]; cntg[n0 + t] = cnt[t]; }
    }
    __syncthreads();
    // pass 2: place (no atomic)
    for (int i = t; i < m; i += 1024) {
        unsigned int e = padded[base + i];
        int local = (int)(e >> 16) - n0;
        eo[sstart[local] + rnk[i]] = (unsigned short)(e & 0xFFFFu);
    }
    __syncthreads();                              // rnk dead
    for (int i = t; i < m; i += 1024) csr16[base + i] = eo[i];
    // degree-descending perm (comparison rank; phantoms t>=NPB have cnt 0)
    if (t < 256) {
        int d = scnt[t], rank = 0;
        for (int j2 = 0; j2 < 256; ++j2) {
            int dj = scnt[j2];
            rank += (dj > d) || (dj == d && j2 < t);
        }
        sperm[rank] = (unsigned short)t;
    }
    __syncthreads();
    // gather: 4 lanes/node over LDS eo, register accumulation
    {
        int slot = t >> 2, q = t & 3;
        int nl = sperm[slot];
        bool ok = nl < NPB;
        float a[HID];
        #pragma unroll
        for (int j = 0; j < HID; ++j) a[j] = 0.f;
        if (ok) {
            int cb = sstart[nl], ce = cb + scnt[nl];
            #pragma unroll 2
            for (int k = cb + q; k < ce; k += 4) addrow(y_in, eo[k], a);
            if (q == 0) {
                const float4* ar = (const float4*)(accp + (size_t)(n0 + nl) * HID);
                #pragma unroll
                for (int qq = 0; qq < 5; ++qq) {
                    float4 v = ar[qq];
                    a[qq*4+0] += v.x; a[qq*4+1] += v.y; a[qq*4+2] += v.z; a[qq*4+3] += v.w;
                }
            }
        }
        if (ok && (q == 0 || q == 2)) {
            float* dstp = (q == 0) ? rh : rh2;
            #pragma unroll
            for (int qq = 0; qq < 5; ++qq)
                *(float4*)&dstp[nl * HID + qq * 4] =
                    make_float4(a[qq*4], a[qq*4+1], a[qq*4+2], a[qq*4+3]);
        }
        __syncthreads();
        if (ok && (q == 1 || q == 3)) {
            float* dstp = (q == 1) ? rh : rh2;
            #pragma unroll
            for (int qq = 0; qq < 5; ++qq) {
                float4 v = *(float4*)&dstp[nl * HID + qq * 4];
                v.x += a[qq*4]; v.y += a[qq*4+1]; v.z += a[qq*4+2]; v.w += a[qq*4+3];
                *(float4*)&dstp[nl * HID + qq * 4] = v;
            }
        }
        __syncthreads();
    }
    // gemm2
    for (int i = t; i < NPB * 5; i += 1024) {
        int n = i / 5, j0 = (i % 5) * 4;
        float y0 = 0.f, y1 = 0.f, y2 = 0.f, y3 = 0.f;
        float c0 = sb[j0], c1 = sb[j0+1], c2 = sb[j0+2], c3 = sb[j0+3];
        #pragma unroll
        for (int k = 0; k < HID; ++k) {
            float h = fmaxf(rh[n * HID + k] + rh2[n * HID + k], 0.f);
            const float* wr = sWrel  + k * HID + j0;
            const float* wo = sWroot + k * HID + j0;
            y0 = fmaf(h, wr[0], y0); y1 = fmaf(h, wr[1], y1);
            y2 = fmaf(h, wr[2], y2); y3 = fmaf(h, wr[3], y3);
            c0 = fmaf(h, wo[0], c0); c1 = fmaf(h, wo[1], c1);
            c2 = fmaf(h, wo[2], c2); c3 = fmaf(h, wo[3], c3);
        }
        *(uint2*)(y_out + (size_t)(n0 + n) * YSTR + j0) = make_uint2(pk2(y0, y1), pk2(y2, y3));
        *(float4*)(acc_out + (size_t)(n0 + n) * HID + j0) = make_float4(c0, c1, c2, c3);
    }
}

// ================= K3: gather (100 nodes, local LPT, 4 lanes/node) + gemm3 ==========

__global__ __launch_bounds__(512) void k3_gather_gemm(
        const int* __restrict__ startg, const int* __restrict__ cntg,
        const unsigned short* __restrict__ csr16,
        const unsigned short* __restrict__ y_in, const float* __restrict__ accp,
        const float* __restrict__ Wrel, const float* __restrict__ Wroot,
        const float* __restrict__ bb,
        unsigned short* __restrict__ y_out, float* __restrict__ acc_out) {
    __shared__ float rh[NPB3 * HID];     // 8000 B
    __shared__ float rh2[NPB3 * HID];    // 8000 B
    __shared__ float sWrel[HID * HID], sWroot[HID * HID], sb[HID];
    __shared__ int sstart[128], scnt[128];
    __shared__ unsigned short sperm[128];
    int g = blockIdx.x, t = threadIdx.x;
    int n0 = g * NPB3;
    for (int i = t; i < HID * HID; i += 512) { sWrel[i] = Wrel[i]; sWroot[i] = Wroot[i]; }
    if (t < HID) sb[t] = bb[t];
    if (t < 128) {
        scnt[t]   = (t < NPB3) ? cntg[n0 + t] : -1;
        sstart[t] = (t < NPB3) ? startg[n0 + t] : 0;
    }
    __syncthreads();
    if (t < 128) {        // local degree-descending perm
        int d = scnt[t], rank = 0;
        for (int j2 = 0; j2 < 128; ++j2) {
            int dj = scnt[j2];
            rank += (dj > d) || (dj == d && j2 < t);
        }
        sperm[rank] = (unsigned short)t;
    }
    __syncthreads();
    {
        int slot = t >> 2, q = t & 3;
        int nl = sperm[slot];
        bool ok = nl < NPB3;
        float a[HID];
        #pragma unroll
        for (int j = 0; j < HID; ++j) a[j] = 0.f;
        if (ok) {
            int cb = sstart[nl], ce = cb + scnt[nl];
            #pragma unroll 2
            for (int k = cb + q; k < ce; k += 4) addrow(y_in, csr16[k], a);
            if (q == 0) {
                const float4* ar = (const float4*)(accp + (size_t)(n0 + nl) * HID);
                #pragma unroll
                for (int qq = 0; qq < 5; ++qq) {
                    float4 v = ar[qq];
                    a[qq*4+0] += v.x; a[qq*4+1] += v.y; a[qq*4+2] += v.z; a[qq*4+3] += v.w;
                }
            }
        }
        if (ok && (q == 0 || q == 2)) {
            float* dstp = (q == 0) ? rh : rh2;
            #pragma unroll
            for (int qq = 0; qq < 5; ++qq)
                *(float4*)&dstp[nl * HID + qq * 4] =
                    make_float4(a[qq*4], a[qq*4+1], a[qq*4+2], a[qq*4+3]);
        }
        __syncthreads();
        if (ok && (q == 1 || q == 3)) {
            float* dstp = (q == 1) ? rh : rh2;
            #pragma unroll
            for (int qq = 0; qq < 5; ++qq) {
                float4 v = *(float4*)&dstp[nl * HID + qq * 4];
                v.x += a[qq*4]; v.y += a[qq*4+1]; v.z += a[qq*4+2]; v.w += a[qq*4+3];
                *(float4*)&dstp[nl * HID + qq * 4] = v;
            }
        }
        __syncthreads();
    }
    for (int i = t; i < NPB3 * 5; i += 512) {
        int n = i / 5, j0 = (i % 5) * 4;
        float y0 = 0.f, y1 = 0.f, y2 = 0.f, y3 = 0.f;
        float c0 = sb[j0], c1 = sb[j0+1], c2 = sb[j0+2], c3 = sb[j0+3];
        #pragma unroll
        for (int k = 0; k < HID; ++k) {
            float h = fmaxf(rh[n * HID + k] + rh2[n * HID + k], 0.f);
            const float* wr = sWrel  + k * HID + j0;
            const float* wo = sWroot + k * HID + j0;
            y0 = fmaf(h, wr[0], y0); y1 = fmaf(h, wr[1], y1);
            y2 = fmaf(h, wr[2], y2); y3 = fmaf(h, wr[3], y3);
            c0 = fmaf(h, wo[0], c0); c1 = fmaf(h, wo[1], c1);
            c2 = fmaf(h, wo[2], c2); c3 = fmaf(h, wo[3], c3);
        }
        *(uint2*)(y_out + (size_t)(n0 + n) * YSTR + j0) = make_uint2(pk2(y0, y1), pk2(y2, y3));
        *(float4*)(acc_out + (size_t)(n0 + n) * HID + j0) = make_float4(c0, c1, c2, c3);
    }
}

// ================= K4: gather + pooling (contiguous window) + final linear ==========

__global__ __launch_bounds__(512) void k4_gather_pool(
        const int* __restrict__ startg, const int* __restrict__ cntg,
        const unsigned short* __restrict__ csr16,
        const unsigned short* __restrict__ y_in, const float* __restrict__ accp,
        const int* __restrict__ batch,
        float* __restrict__ gmax, float* __restrict__ gsum, float* __restrict__ gcnt,
        int* __restrict__ done, const float* __restrict__ Wlin,
        const float* __restrict__ blin, float* __restrict__ out) {
    __shared__ float rh[NPB3 * HID];
    __shared__ float rh2[NPB3 * HID];
    __shared__ float redm[26 * HID], reds[26 * HID];
    __shared__ int sstart[128], scnt[128];
    __shared__ unsigned short sperm[128];
    __shared__ int sbatch[NPB3];
    __shared__ int seglo[16], seghi[16];
    __shared__ int lastFlag;
    int g = blockIdx.x, t = threadIdx.x;
    int n0 = g * NPB3;
    if (t < 128) {
        scnt[t]   = (t < NPB3) ? cntg[n0 + t] : -1;
        sstart[t] = (t < NPB3) ? startg[n0 + t] : 0;
    }
    if (t < NPB3) sbatch[t] = batch[n0 + t];
    __syncthreads();
    if (t < 128) {
        int d = scnt[t], rank = 0;
        for (int j2 = 0; j2 < 128; ++j2) {
            int dj = scnt[j2];
            rank += (dj > d) || (dj == d && j2 < t);
        }
        sperm[rank] = (unsigned short)t;
    }
    __syncthreads();
    {
        int slot = t >> 2, q = t & 3;
        int nl = sperm[slot];
        bool ok = nl < NPB3;
        float a[HID];
        #pragma unroll
        for (int j = 0; j < HID; ++j) a[j] = 0.f;
        if (ok) {
            int cb = sstart[nl], ce = cb + scnt[nl];
            #pragma unroll 2
            for (int k = cb + q; k < ce; k += 4) addrow(y_in, csr16[k], a);
            if (q == 0) {
                const float4* ar = (const float4*)(accp + (size_t)(n0 + nl) * HID);
                #pragma unroll
                for (int qq = 0; qq < 5; ++qq) {
                    float4 v = ar[qq];
                    a[qq*4+0] += v.x; a[qq*4+1] += v.y; a[qq*4+2] += v.z; a[qq*4+3] += v.w;
                }
            }
        }
        if (ok && (q == 0 || q == 2)) {
            float* dstp = (q == 0) ? rh : rh2;
            #pragma unroll
            for (int qq = 0; qq < 5; ++qq)
                *(float4*)&dstp[nl * HID + qq * 4] =
                    make_float4(a[qq*4], a[qq*4+1], a[qq*4+2], a[qq*4+3]);
        }
        __syncthreads();
        if (ok && (q == 1 || q == 3)) {
            float* dstp = (q == 1) ? rh : rh2;
            #pragma unroll
            for (int qq = 0; qq < 5; ++qq) {
                float4 v = *(float4*)&dstp[nl * HID + qq * 4];
                v.x += a[qq*4]; v.y += a[qq*4+1]; v.z += a[qq*4+2]; v.w += a[qq*4+3];
                *(float4*)&dstp[nl * HID + qq * 4] = v;
            }
        }
        __syncthreads();
    }
    // segmented pooling over contiguous nodes (batch sorted; span <= 2 expected)
    int g0 = sbatch[0];
    int span = sbatch[NPB3 - 1] - g0 + 1;
    if (t < NPB3) {
        int bi = sbatch[t] - g0;
        if (bi < 16) {
            if (t == 0 || sbatch[t - 1] != sbatch[t]) seglo[bi] = t;
            if (t == NPB3 - 1 || sbatch[t + 1] != sbatch[t]) seghi[bi] = t + 1;
        }
    }
    __syncthreads();
    if (span > 16) span = 16;
    for (int li = 0; li < span; ++li) {
        int lo = seglo[li], hi = seghi[li];
        int r = t / HID, j = t % HID;
        if (r < 25) {
            float mx = 0.f, sm = 0.f;
            for (int n = lo + r; n < hi; n += 25) {
                float v = fmaxf(rh[n * HID + j] + rh2[n * HID + j], 0.f);
                mx = fmaxf(mx, v); sm += v;
            }
            redm[r * HID + j] = mx; reds[r * HID + j] = sm;
        }
        __syncthreads();
        if (t < HID) {
            float mm = 0.f, ss = 0.f;
            #pragma unroll
            for (int r2 = 0; r2 < 25; ++r2) {
                mm = fmaxf(mm, redm[r2 * HID + t]);
                ss += reds[r2 * HID + t];
            }
            atomicMax((int*)&gmax[(g0 + li) * HID + t], __float_as_int(mm));
            atomicAdd(&gsum[(g0 + li) * HID + t], ss);
        }
        if (t == HID) atomicAdd(&gcnt[g0 + li], (float)(hi - lo));
        __syncthreads();
    }
    // last block: final linear (STRIDED: 640 outputs > 512 threads — R11 bug fix)
    if (t == 0) {
        __threadfence();
        lastFlag = (atomicAdd(done, 1) == NBLK3 - 1);
    }
    __syncthreads();
    if (!lastFlag) return;
    __threadfence();
    float* sW = redm;
    for (int i = t; i < 2 * HID * OUT_DIM; i += 512) sW[i] = Wlin[i];
    __syncthreads();
    for (int idx = t; idx < N_GRAPHS * OUT_DIM; idx += 512) {
        int gg = idx / OUT_DIM, o = idx % OUT_DIM;
        float c = fmaxf(gcnt[gg], 1.0f);
        float av = blin[o];
        #pragma unroll
        for (int j = 0; j < HID; ++j) {
            av = fmaf(gmax[gg * HID + j], sW[j * OUT_DIM + o], av);
            av = fmaf(gsum[gg * HID + j] / c, sW[(HID + j) * OUT_DIM + o], av);
        }
        out[idx] = av;
    }
}

extern "C" void kernel_launch(void* const* d_in, const int* in_sizes, int n_in,
                              void* d_out, int out_size, void* d_ws, size_t ws_size,
                              hipStream_t stream) {
    const float* x      = (const float*)d_in[0];
    const int*   ei     = (const int*)  d_in[1];
    const int*   batch  = (const int*)  d_in[2];
    const float* Wrel1  = (const float*)d_in[3];
    const float* Wroot1 = (const float*)d_in[4];
    const float* b1     = (const float*)d_in[5];
    const float* Wrel2  = (const float*)d_in[6];
    const float* Wroot2 = (const float*)d_in[7];
    const float* b2     = (const float*)d_in[8];
    const float* Wrel3  = (const float*)d_in[9];
    const float* Wroot3 = (const float*)d_in[10];
    const float* b3     = (const float*)d_in[11];
    const float* Wlin   = (const float*)d_in[12];
    const float* blin   = (const float*)d_in[13];
    float* out = (float*)d_out;

    char* ws = (char*)d_ws;
    const size_t YB = (size_t)N_NODES * YSTR * 2;                   // 3,200,000 (bf16)
    const size_t AB = (size_t)N_NODES * HID * 4;                    // 4,000,000
    const size_t PB = (size_t)NBUCK * BCAP * 4;                     // 8,192,000
    const size_t CB = (size_t)NBUCK * BCAP * 2;                     // 4,096,000
    unsigned short* yA     = (unsigned short*)(ws);
    unsigned short* yB     = (unsigned short*)(ws + YB);
    float*          accA   = (float*)(ws + 2 * YB);
    float*          accB   = (float*)(ws + 2 * YB + AB);
    unsigned int*   padded = (unsigned int*)(ws + 2 * YB + 2 * AB);
    unsigned short* csr16  = (unsigned short*)(ws + 2 * YB + 2 * AB + PB);
    int*            startg = (int*)(ws + 2 * YB + 2 * AB + PB + CB);
    int*            cntg   = startg + N_NODES;
    int*            gcur   = cntg + N_NODES;
    int*            done   = gcur + NBUCK;
    float*          gmax   = (float*)(done + 4);
    float*          gsum   = gmax + N_GRAPHS * HID;
    float*          gcnt   = gsum + N_GRAPHS * HID;

    const int* src = ei;
    const int* dst = ei + N_EDGES;

    hipMemsetAsync(gcur, 0, (NBUCK + 4) * sizeof(int), stream);
    // K1: scatter (blocks 0-255) || gemm50 -> bf16 y
    k1_scatter_gemm<<<256 + GEMMB, 1024, 0, stream>>>(dst, src, gcur, padded,
                                                      x, Wrel1, Wroot1, b1, yA, accA,
                                                      gmax, gsum, gcnt);
    // K2: counting sort + perm + L1 gather (4 lanes/node) + gemm2
    k2_build_gather<<<NBUCK, 1024, 0, stream>>>(gcur, padded, csr16, startg, cntg,
                                                yA, accA, Wrel2, Wroot2, b2, yB, accB);
    // K3: L2 gather (100 nodes/block, local LPT) + gemm3
    k3_gather_gemm<<<NBLK3, 512, 0, stream>>>(startg, cntg, csr16,
                                              yB, accB, Wrel3, Wroot3, b3, yA, accA);
    // K4: L3 gather + pooling + fused final linear
    k4_gather_pool<<<NBLK3, 512, 0, stream>>>(startg, cntg, csr16,
                                              yA, accA, batch, gmax, gsum, gcnt,
                                              done, Wlin, blin, out);
}

// Round 13
// 119.991 us; speedup vs baseline: 1.3826x; 1.0634x over previous
//
#include <hip/hip_runtime.h>

#define N_NODES  50000
#define N_EDGES  1600000
#define N_FEAT   50
#define HID      20
#define OUT_DIM  10
#define N_GRAPHS 64

#define NBUCK 196            // buckets: dst >> 8, 256 nodes each
#define BCAP  10240          // padded slots/bucket (avg 8163, ~23 sigma)
#define EPB   6250           // edges per scatter block (N_EDGES/256)
#define YSTR  32             // bf16 elements per y row -> 64 B, one cache line
#define GEMMB 977            // ceil(N_NODES*HID/1024)

__device__ __forceinline__ unsigned short f2bf(float f) {
    unsigned int u = __float_as_uint(f);
    u += 0x7FFFu + ((u >> 16) & 1u);          // round-to-nearest-even
    return (unsigned short)(u >> 16);
}
__device__ __forceinline__ unsigned int pk2(float f0, float f1) {
    return (unsigned int)f2bf(f0) | ((unsigned int)f2bf(f1) << 16);
}
__device__ __forceinline__ float blo(unsigned int u) { return __uint_as_float(u << 16); }
__device__ __forceinline__ float bhi(unsigned int u) { return __uint_as_float(u & 0xFFFF0000u); }

// add one bf16 message row (20 values, one 64B line) into 20 f32 registers
__device__ __forceinline__ void addrow(const unsigned short* __restrict__ yb,
                                       int sn, float* a) {
    const unsigned short* p = yb + (size_t)sn * YSTR;
    uint4 q0 = *(const uint4*)(p);        // values 0-7
    uint4 q1 = *(const uint4*)(p + 8);    // values 8-15
    uint2 q2 = *(const uint2*)(p + 16);   // values 16-19
    a[0] += blo(q0.x); a[1] += bhi(q0.x); a[2] += blo(q0.y); a[3] += bhi(q0.y);
    a[4] += blo(q0.z); a[5] += bhi(q0.z); a[6] += blo(q0.w); a[7] += bhi(q0.w);
    a[8] += blo(q1.x); a[9] += bhi(q1.x); a[10] += blo(q1.y); a[11] += bhi(q1.y);
    a[12] += blo(q1.z); a[13] += bhi(q1.z); a[14] += blo(q1.w); a[15] += bhi(q1.w);
    a[16] += blo(q2.x); a[17] += bhi(q2.x); a[18] += blo(q2.y); a[19] += bhi(q2.y);
}

// ================= K1: bucket scatter (rank trick + coalesced write) || gemm50 ======

__global__ __launch_bounds__(1024) void k1_scatter_gemm(
        const int* __restrict__ dst, const int* __restrict__ srcv,
        int* __restrict__ gcur, unsigned int* __restrict__ padded,
        const float* __restrict__ x, const float* __restrict__ Wrel,
        const float* __restrict__ Wroot, const float* __restrict__ bb,
        unsigned short* __restrict__ y, float* __restrict__ acc,
        float* __restrict__ gmax, float* __restrict__ gsum, float* __restrict__ gcnt) {
    __shared__ char smem[41728];
    int t = threadIdx.x;
    if (blockIdx.x < 256) {
        unsigned short* rnk = (unsigned short*)smem;           // 12500 B
        unsigned int*   ep2 = (unsigned int*)(smem + 12544);   // 25000 B
        int* cnt   = (int*)(smem + 37632);
        int* scn   = cnt + 256;
        int* lofs  = scn + 256;
        int* gbase = lofs + 256;
        if (blockIdx.x == 0) {
            for (int i = t; i < N_GRAPHS * HID; i += 1024) { gmax[i] = 0.f; gsum[i] = 0.f; }
            if (t < N_GRAPHS) gcnt[t] = 0.f;
        }
        if (t < 256) cnt[t] = 0;
        __syncthreads();
        int e0 = blockIdx.x * EPB;
        // pass 1: rank within bucket (1 LDS atomic/edge)
        for (int i = t; i < EPB; i += 1024) {
            unsigned int d = (unsigned int)dst[e0 + i];
            rnk[i] = (unsigned short)atomicAdd(&cnt[d >> 8], 1);
        }
        __syncthreads();
        if (t < 256) scn[t] = cnt[t];
        __syncthreads();
        for (int d2 = 1; d2 < 256; d2 <<= 1) {
            int u = 0;
            if (t < 256 && t >= d2) u = scn[t - d2];
            __syncthreads();
            if (t < 256) scn[t] += u;
            __syncthreads();
        }
        if (t < 256) lofs[t] = scn[t] - cnt[t];
        if (t < NBUCK) gbase[t] = t * BCAP + atomicAdd(&gcur[t], cnt[t]);
        __syncthreads();
        // pass 2: re-read (L2-hot), place into bucket-grouped LDS (no atomic)
        for (int i = t; i < EPB; i += 1024) {
            unsigned int d = (unsigned int)dst[e0 + i];
            unsigned int s = (unsigned int)srcv[e0 + i];
            ep2[lofs[d >> 8] + rnk[i]] = (d << 16) | s;
        }
        __syncthreads();
        // pass 3: coalesced global write
        for (int i = t; i < EPB; i += 1024) {
            unsigned int e = ep2[i];
            int bk = e >> 24;
            int gp = gbase[bk] + (i - lofs[bk]);
            if (gp < (bk + 1) * BCAP) padded[gp] = e;  // guard never fires
        }
    } else {
        float* sWrel  = (float*)smem;
        float* sWroot = sWrel + N_FEAT * HID;
        for (int i = t; i < N_FEAT * HID; i += 1024) { sWrel[i] = Wrel[i]; sWroot[i] = Wroot[i]; }
        __syncthreads();
        int idx = (blockIdx.x - 256) * 1024 + t;
        if (idx < N_NODES * HID) {
            int n = idx / HID, j = idx % HID;
            const float* xr = x + n * N_FEAT;
            float a0 = 0.f, a1 = bb[j];
            #pragma unroll
            for (int k = 0; k < N_FEAT; ++k) {
                float xv = xr[k];
                a0 = fmaf(xv, sWrel[k * HID + j], a0);
                a1 = fmaf(xv, sWroot[k * HID + j], a1);
            }
            y[(size_t)n * YSTR + j] = f2bf(a0);
            acc[idx] = a1;
        }
    }
}

// ================= K2: counting sort + perm + gather1 (4 lanes/node) + gemm2 ========

__global__ __launch_bounds__(1024) void k2_build_gather(
        const int* __restrict__ gcur, const unsigned int* __restrict__ padded,
        unsigned short* __restrict__ csr16, int* __restrict__ startg,
        int* __restrict__ cntg, unsigned short* __restrict__ permg,
        const unsigned short* __restrict__ y_in, const float* __restrict__ accp,
        const float* __restrict__ Wrel, const float* __restrict__ Wroot,
        const float* __restrict__ bb,
        unsigned short* __restrict__ y_out, float* __restrict__ acc_out) {
    __shared__ unsigned short eo[BCAP];          // 20 KB sorted src lists
    __shared__ char uni[20480];                  // rnk (sort) then rh (gather)
    __shared__ float sWrel[HID * HID], sWroot[HID * HID], sb[HID];
    __shared__ int cnt[256], scn[256], s_start[256], s_cnt[256];
    __shared__ unsigned short sperm[256];
    unsigned short* rnk = (unsigned short*)uni;
    float*          rh  = (float*)uni;
    int g = blockIdx.x, t = threadIdx.x;
    int base = g * BCAP;
    int m = min(gcur[g], BCAP);
    int n0 = g * 256;
    int nvalid = min(256, N_NODES - n0);
    for (int i = t; i < HID * HID; i += 1024) { sWrel[i] = Wrel[i]; sWroot[i] = Wroot[i]; }
    if (t < HID) sb[t] = bb[t];
    if (t < 256) cnt[t] = 0;
    __syncthreads();
    // rank within node
    for (int i = t; i < m; i += 1024) {
        int local = (padded[base + i] >> 16) & 255;
        rnk[i] = (unsigned short)atomicAdd(&cnt[local], 1);
    }
    __syncthreads();
    if (t < 256) { s_cnt[t] = cnt[t]; scn[t] = cnt[t]; }
    __syncthreads();
    for (int d = 1; d < 256; d <<= 1) {
        int u = 0;
        if (t < 256 && t >= d) u = scn[t - d];
        __syncthreads();
        if (t < 256) scn[t] += u;
        __syncthreads();
    }
    if (t < 256) {
        s_start[t] = scn[t] - s_cnt[t];
        if (t < nvalid) { startg[n0 + t] = base + s_start[t]; cntg[n0 + t] = s_cnt[t]; }
    }
    __syncthreads();
    // place (no atomic)
    for (int i = t; i < m; i += 1024) {
        unsigned int e = padded[base + i];
        int local = (e >> 16) & 255;
        eo[s_start[local] + rnk[i]] = (unsigned short)(e & 0xFFFFu);
    }
    __syncthreads();                              // rnk dead after here
    for (int i = t; i < m; i += 1024) csr16[base + i] = eo[i];
    // degree-descending perm by comparison rank
    if (t < 256) {
        int d = s_cnt[t], rank = 0;
        for (int j2 = 0; j2 < 256; ++j2) {
            int dj = s_cnt[j2];
            rank += (dj > d) || (dj == d && j2 < t);
        }
        sperm[rank] = (unsigned short)t;
    }
    __syncthreads();
    if (t < 256) permg[g * 256 + t] = sperm[t];
    // gather: 4 lanes per node (all 1024 threads active), staged combine into rh
    {
        int slot = t >> 2, q = t & 3;             // slot 0..255
        int nl = sperm[slot];
        bool ok = nl < nvalid;
        float a[HID];
        #pragma unroll
        for (int j = 0; j < HID; ++j) a[j] = 0.f;
        if (ok) {
            int a0 = s_start[nl], cn = s_cnt[nl];
            #pragma unroll 2
            for (int k = q; k < cn; k += 4) addrow(y_in, eo[a0 + k], a);
            if (q == 0) {
                const float4* ar = (const float4*)(accp + (size_t)(n0 + nl) * HID);
                #pragma unroll
                for (int qq = 0; qq < 5; ++qq) {
                    float4 v = ar[qq];
                    a[qq*4+0] += v.x; a[qq*4+1] += v.y; a[qq*4+2] += v.z; a[qq*4+3] += v.w;
                }
            }
        }
        // rh still holds rnk garbage: stage 0 overwrites, stages 1-3 accumulate
        #pragma unroll
        for (int s = 0; s < 4; ++s) {
            if (ok && q == s) {
                if (s == 0) {
                    #pragma unroll
                    for (int qq = 0; qq < 5; ++qq)
                        *(float4*)&rh[nl * HID + qq * 4] =
                            make_float4(a[qq*4], a[qq*4+1], a[qq*4+2], a[qq*4+3]);
                } else {
                    #pragma unroll
                    for (int qq = 0; qq < 5; ++qq) {
                        float4 v = *(float4*)&rh[nl * HID + qq * 4];
                        v.x += a[qq*4]; v.y += a[qq*4+1];
                        v.z += a[qq*4+2]; v.w += a[qq*4+3];
                        *(float4*)&rh[nl * HID + qq * 4] = v;
                    }
                }
            }
            __syncthreads();
        }
    }
    // gemm2 from LDS
    for (int i = t; i < nvalid * 5; i += 1024) {
        int n = i / 5, j0 = (i % 5) * 4;
        float y0 = 0.f, y1 = 0.f, y2 = 0.f, y3 = 0.f;
        float c0 = sb[j0], c1 = sb[j0+1], c2 = sb[j0+2], c3 = sb[j0+3];
        #pragma unroll
        for (int k = 0; k < HID; ++k) {
            float h = fmaxf(rh[n * HID + k], 0.f);
            const float* wr = sWrel  + k * HID + j0;
            const float* wo = sWroot + k * HID + j0;
            y0 = fmaf(h, wr[0], y0); y1 = fmaf(h, wr[1], y1);
            y2 = fmaf(h, wr[2], y2); y3 = fmaf(h, wr[3], y3);
            c0 = fmaf(h, wo[0], c0); c1 = fmaf(h, wo[1], c1);
            c2 = fmaf(h, wo[2], c2); c3 = fmaf(h, wo[3], c3);
        }
        *(uint2*)(y_out + (size_t)(n0 + n) * YSTR + j0) = make_uint2(pk2(y0, y1), pk2(y2, y3));
        *(float4*)(acc_out + (size_t)(n0 + n) * HID + j0) = make_float4(c0, c1, c2, c3);
    }
}

// ================= K3: gather (4 lanes/node, global csr) + gemm3 ====================

__global__ __launch_bounds__(1024) void k3_gather_gemm(
        const int* __restrict__ startg, const int* __restrict__ cntg,
        const unsigned short* __restrict__ csr16, const unsigned short* __restrict__ permg,
        const unsigned short* __restrict__ y_in, const float* __restrict__ accp,
        const float* __restrict__ Wrel, const float* __restrict__ Wroot,
        const float* __restrict__ bb,
        unsigned short* __restrict__ y_out, float* __restrict__ acc_out) {
    __shared__ float rh[256 * HID];
    __shared__ float rh2[256 * HID];
    __shared__ float sWrel[HID * HID], sWroot[HID * HID], sb[HID];
    __shared__ unsigned short sperm[256];
    int g = blockIdx.x, t = threadIdx.x;
    int n0 = g * 256;
    int nvalid = min(256, N_NODES - n0);
    for (int i = t; i < HID * HID; i += 1024) { sWrel[i] = Wrel[i]; sWroot[i] = Wroot[i]; }
    if (t < HID) sb[t] = bb[t];
    if (t < 256) sperm[t] = permg[g * 256 + t];
    __syncthreads();
    int slot = t >> 2, q = t & 3;
    int nl = sperm[slot];
    bool ok = nl < nvalid;
    float a[HID];
    #pragma unroll
    for (int j = 0; j < HID; ++j) a[j] = 0.f;
    if (ok) {
        int node = n0 + nl;
        int a0 = startg[node], cn = cntg[node];
        #pragma unroll 2
        for (int k = q; k < cn; k += 4) addrow(y_in, csr16[a0 + k], a);
        if (q == 0) {
            const float4* ar = (const float4*)(accp + (size_t)node * HID);
            #pragma unroll
            for (int qq = 0; qq < 5; ++qq) {
                float4 v = ar[qq];
                a[qq*4+0] += v.x; a[qq*4+1] += v.y; a[qq*4+2] += v.z; a[qq*4+3] += v.w;
            }
        }
    }
    if (ok && (q == 0 || q == 2)) {
        float* dstp = (q == 0) ? rh : rh2;
        #pragma unroll
        for (int qq = 0; qq < 5; ++qq)
            *(float4*)&dstp[nl * HID + qq * 4] =
                make_float4(a[qq*4], a[qq*4+1], a[qq*4+2], a[qq*4+3]);
    }
    __syncthreads();
    if (ok && (q == 1 || q == 3)) {
        float* dstp = (q == 1) ? rh : rh2;
        #pragma unroll
        for (int qq = 0; qq < 5; ++qq) {
            float4 v = *(float4*)&dstp[nl * HID + qq * 4];
            v.x += a[qq*4]; v.y += a[qq*4+1]; v.z += a[qq*4+2]; v.w += a[qq*4+3];
            *(float4*)&dstp[nl * HID + qq * 4] = v;
        }
    }
    __syncthreads();
    for (int i = t; i < nvalid * 5; i += 1024) {
        int n = i / 5, j0 = (i % 5) * 4;
        float y0 = 0.f, y1 = 0.f, y2 = 0.f, y3 = 0.f;
        float c0 = sb[j0], c1 = sb[j0+1], c2 = sb[j0+2], c3 = sb[j0+3];
        #pragma unroll
        for (int k = 0; k < HID; ++k) {
            float h = fmaxf(rh[n * HID + k] + rh2[n * HID + k], 0.f);
            const float* wr = sWrel  + k * HID + j0;
            const float* wo = sWroot + k * HID + j0;
            y0 = fmaf(h, wr[0], y0); y1 = fmaf(h, wr[1], y1);
            y2 = fmaf(h, wr[2], y2); y3 = fmaf(h, wr[3], y3);
            c0 = fmaf(h, wo[0], c0); c1 = fmaf(h, wo[1], c1);
            c2 = fmaf(h, wo[2], c2); c3 = fmaf(h, wo[3], c3);
        }
        *(uint2*)(y_out + (size_t)(n0 + n) * YSTR + j0) = make_uint2(pk2(y0, y1), pk2(y2, y3));
        *(float4*)(acc_out + (size_t)(n0 + n) * HID + j0) = make_float4(c0, c1, c2, c3);
    }
}

// ================= K4: gather (4 lanes/node) + pooling + last-block final linear ====

__global__ __launch_bounds__(1024) void k4_gather_pool(
        const int* __restrict__ startg, const int* __restrict__ cntg,
        const unsigned short* __restrict__ csr16, const unsigned short* __restrict__ permg,
        const unsigned short* __restrict__ y_in, const float* __restrict__ accp,
        const int* __restrict__ batch,
        float* __restrict__ gmax, float* __restrict__ gsum, float* __restrict__ gcnt,
        int* __restrict__ done, const float* __restrict__ Wlin,
        const float* __restrict__ blin, float* __restrict__ out) {
    __shared__ float rh[256 * HID];
    __shared__ float rh2[256 * HID];
    __shared__ float redm[51 * HID], reds[51 * HID];
    __shared__ unsigned short sperm[256];
    __shared__ int sbatch[256];
    __shared__ int seglo[16], seghi[16];
    __shared__ int lastFlag;
    int g = blockIdx.x, t = threadIdx.x;
    int n0 = g * 256;
    int nvalid = min(256, N_NODES - n0);
    if (t < 256) sperm[t] = permg[g * 256 + t];
    if (t < nvalid) sbatch[t] = batch[n0 + t];
    __syncthreads();
    int slot = t >> 2, q = t & 3;
    int nl = sperm[slot];
    bool ok = nl < nvalid;
    float a[HID];
    #pragma unroll
    for (int j = 0; j < HID; ++j) a[j] = 0.f;
    if (ok) {
        int node = n0 + nl;
        int a0 = startg[node], cn = cntg[node];
        #pragma unroll 2
        for (int k = q; k < cn; k += 4) addrow(y_in, csr16[a0 + k], a);
        if (q == 0) {
            const float4* ar = (const float4*)(accp + (size_t)node * HID);
            #pragma unroll
            for (int qq = 0; qq < 5; ++qq) {
                float4 v = ar[qq];
                a[qq*4+0] += v.x; a[qq*4+1] += v.y; a[qq*4+2] += v.z; a[qq*4+3] += v.w;
            }
        }
    }
    if (ok && (q == 0 || q == 2)) {
        float* dstp = (q == 0) ? rh : rh2;
        #pragma unroll
        for (int qq = 0; qq < 5; ++qq)
            *(float4*)&dstp[nl * HID + qq * 4] =
                make_float4(a[qq*4], a[qq*4+1], a[qq*4+2], a[qq*4+3]);
    }
    __syncthreads();
    if (ok && (q == 1 || q == 3)) {
        float* dstp = (q == 1) ? rh : rh2;
        #pragma unroll
        for (int qq = 0; qq < 5; ++qq) {
            float4 v = *(float4*)&dstp[nl * HID + qq * 4];
            v.x += a[qq*4]; v.y += a[qq*4+1]; v.z += a[qq*4+2]; v.w += a[qq*4+3];
            *(float4*)&dstp[nl * HID + qq * 4] = v;
        }
    }
    __syncthreads();
    // segmented max/mean pooling (batch sorted)
    int g0 = sbatch[0];
    int span = sbatch[nvalid - 1] - g0 + 1;
    if (t < nvalid) {
        int bi = sbatch[t] - g0;
        if (bi < 16) {
            if (t == 0 || sbatch[t - 1] != sbatch[t]) seglo[bi] = t;
            if (t == nvalid - 1 || sbatch[t + 1] != sbatch[t]) seghi[bi] = t + 1;
        }
    }
    __syncthreads();
    if (span > 16) span = 16;
    for (int li = 0; li < span; ++li) {
        int lo = seglo[li], hi = seghi[li];
        int r = t / HID, j = t % HID;
        if (r < 51) {
            float mx = 0.f, sm = 0.f;
            for (int n = lo + r; n < hi; n += 51) {
                float v = fmaxf(rh[n * HID + j] + rh2[n * HID + j], 0.f);
                mx = fmaxf(mx, v); sm += v;
            }
            redm[r * HID + j] = mx; reds[r * HID + j] = sm;
        }
        __syncthreads();
        if (t < HID) {
            float mm = 0.f, ss = 0.f;
            #pragma unroll 17
            for (int r2 = 0; r2 < 51; ++r2) {
                mm = fmaxf(mm, redm[r2 * HID + t]);
                ss += reds[r2 * HID + t];
            }
            atomicMax((int*)&gmax[(g0 + li) * HID + t], __float_as_int(mm));
            atomicAdd(&gsum[(g0 + li) * HID + t], ss);
        }
        if (t == HID) atomicAdd(&gcnt[g0 + li], (float)(hi - lo));
        __syncthreads();
    }
    // last block: final linear
    if (t == 0) {
        __threadfence();
        lastFlag = (atomicAdd(done, 1) == NBUCK - 1);
    }
    __syncthreads();
    if (!lastFlag) return;
    __threadfence();
    float* sW = redm;
    for (int i = t; i < 2 * HID * OUT_DIM; i += 1024) sW[i] = Wlin[i];
    __syncthreads();
    if (t < N_GRAPHS * OUT_DIM) {
        int gg = t / OUT_DIM, o = t % OUT_DIM;
        float c = fmaxf(gcnt[gg], 1.0f);
        float av = blin[o];
        #pragma unroll
        for (int j = 0; j < HID; ++j) {
            av = fmaf(gmax[gg * HID + j], sW[j * OUT_DIM + o], av);
            av = fmaf(gsum[gg * HID + j] / c, sW[(HID + j) * OUT_DIM + o], av);
        }
        out[t] = av;
    }
}

extern "C" void kernel_launch(void* const* d_in, const int* in_sizes, int n_in,
                              void* d_out, int out_size, void* d_ws, size_t ws_size,
                              hipStream_t stream) {
    const float* x      = (const float*)d_in[0];
    const int*   ei     = (const int*)  d_in[1];
    const int*   batch  = (const int*)  d_in[2];
    const float* Wrel1  = (const float*)d_in[3];
    const float* Wroot1 = (const float*)d_in[4];
    const float* b1     = (const float*)d_in[5];
    const float* Wrel2  = (const float*)d_in[6];
    const float* Wroot2 = (const float*)d_in[7];
    const float* b2     = (const float*)d_in[8];
    const float* Wrel3  = (const float*)d_in[9];
    const float* Wroot3 = (const float*)d_in[10];
    const float* b3     = (const float*)d_in[11];
    const float* Wlin   = (const float*)d_in[12];
    const float* blin   = (const float*)d_in[13];
    float* out = (float*)d_out;

    char* ws = (char*)d_ws;
    const size_t YB = (size_t)N_NODES * YSTR * 2;                   // 3,200,000 (bf16)
    const size_t AB = (size_t)N_NODES * HID * 4;                    // 4,000,000
    const size_t PB = (size_t)NBUCK * BCAP * 4;                     // 8,028,160
    const size_t CB = (size_t)NBUCK * BCAP * 2;                     // 4,014,080
    const size_t NP = (size_t)NBUCK * 256;                          // 50,176
    unsigned short* yA     = (unsigned short*)(ws);
    unsigned short* yB     = (unsigned short*)(ws + YB);
    float*          accA   = (float*)(ws + 2 * YB);
    float*          accB   = (float*)(ws + 2 * YB + AB);
    unsigned int*   padded = (unsigned int*)(ws + 2 * YB + 2 * AB);
    unsigned short* csr16  = (unsigned short*)(ws + 2 * YB + 2 * AB + PB);
    int*            startg = (int*)(ws + 2 * YB + 2 * AB + PB + CB);
    int*            cntg   = startg + NP;
    unsigned short* permg  = (unsigned short*)(cntg + NP);
    int*            gcur   = (int*)((char*)permg + NP * 2);
    int*            done   = gcur + NBUCK;
    float*          gmax   = (float*)(done + 4);
    float*          gsum   = gmax + N_GRAPHS * HID;
    float*          gcnt   = gsum + N_GRAPHS * HID;

    const int* src = ei;
    const int* dst = ei + N_EDGES;

    hipMemsetAsync(gcur, 0, (NBUCK + 1) * sizeof(int), stream);
    // K1: scatter (blocks 0-255, rank-trick + coalesced write) || gemm50 -> bf16 y
    k1_scatter_gemm<<<256 + GEMMB, 1024, 0, stream>>>(dst, src, gcur, padded,
                                                      x, Wrel1, Wroot1, b1, yA, accA,
                                                      gmax, gsum, gcnt);
    // K2: counting sort + perm + L1 gather (4 lanes/node, LDS src) + gemm2
    k2_build_gather<<<NBUCK, 1024, 0, stream>>>(gcur, padded, csr16, startg, cntg, permg,
                                                yA, accA, Wrel2, Wroot2, b2, yB, accB);
    // K3: L2 gather (4 lanes/node) + gemm3
    k3_gather_gemm<<<NBUCK, 1024, 0, stream>>>(startg, cntg, csr16, permg,
                                               yB, accB, Wrel3, Wroot3, b3, yA, accA);
    // K4: L3 gather + pooling + fused final linear
    k4_gather_pool<<<NBUCK, 1024, 0, stream>>>(startg, cntg, csr16, permg,
                                               yA, accA, batch, gmax, gsum, gcnt,
                                               done, Wlin, blin, out);
}

// Round 14
// 116.981 us; speedup vs baseline: 1.4181x; 1.0257x over previous
//
#include <hip/hip_runtime.h>

#define N_NODES  50000
#define N_EDGES  1600000
#define N_FEAT   50
#define HID      20
#define OUT_DIM  10
#define N_GRAPHS 64

#define NBUCK 196            // buckets: dst >> 8, 256 nodes each
#define BCAP  10240          // padded slots/bucket (avg 8163, ~23 sigma)
#define EPB   6250           // edges per scatter block (N_EDGES/256)
#define YSTR  32             // bf16 elements per y row -> 64 B, one cache line
#define GEMMB 977            // ceil(N_NODES*HID/1024)

__device__ __forceinline__ unsigned short f2bf(float f) {
    unsigned int u = __float_as_uint(f);
    u += 0x7FFFu + ((u >> 16) & 1u);          // round-to-nearest-even
    return (unsigned short)(u >> 16);
}
__device__ __forceinline__ unsigned int pk2(float f0, float f1) {
    return (unsigned int)f2bf(f0) | ((unsigned int)f2bf(f1) << 16);
}
__device__ __forceinline__ float blo(unsigned int u) { return __uint_as_float(u << 16); }
__device__ __forceinline__ float bhi(unsigned int u) { return __uint_as_float(u & 0xFFFF0000u); }

// add one bf16 message row (20 values, one 64B line) into 20 f32 registers
__device__ __forceinline__ void addrow(const unsigned short* __restrict__ yb,
                                       int sn, float* a) {
    const unsigned short* p = yb + (size_t)sn * YSTR;
    uint4 q0 = *(const uint4*)(p);        // values 0-7
    uint4 q1 = *(const uint4*)(p + 8);    // values 8-15
    uint2 q2 = *(const uint2*)(p + 16);   // values 16-19
    a[0] += blo(q0.x); a[1] += bhi(q0.x); a[2] += blo(q0.y); a[3] += bhi(q0.y);
    a[4] += blo(q0.z); a[5] += bhi(q0.z); a[6] += blo(q0.w); a[7] += bhi(q0.w);
    a[8] += blo(q1.x); a[9] += bhi(q1.x); a[10] += blo(q1.y); a[11] += bhi(q1.y);
    a[12] += blo(q1.z); a[13] += bhi(q1.z); a[14] += blo(q1.w); a[15] += bhi(q1.w);
    a[16] += blo(q2.x); a[17] += bhi(q2.x); a[18] += blo(q2.y); a[19] += bhi(q2.y);
}

// ================= K1: bucket scatter (rank trick + coalesced write) || gemm50 ======

__global__ __launch_bounds__(1024) void k1_scatter_gemm(
        const int* __restrict__ dst, const int* __restrict__ srcv,
        int* __restrict__ gcur, unsigned int* __restrict__ padded,
        const float* __restrict__ x, const float* __restrict__ Wrel,
        const float* __restrict__ Wroot, const float* __restrict__ bb,
        unsigned short* __restrict__ y, float* __restrict__ acc,
        float* __restrict__ gmax, float* __restrict__ gsum, float* __restrict__ gcnt) {
    __shared__ char smem[41728];
    int t = threadIdx.x;
    if (blockIdx.x < 256) {
        unsigned short* rnk = (unsigned short*)smem;           // 12500 B
        unsigned int*   ep2 = (unsigned int*)(smem + 12544);   // 25000 B
        int* cnt   = (int*)(smem + 37632);
        int* scn   = cnt + 256;
        int* lofs  = scn + 256;
        int* gbase = lofs + 256;
        if (blockIdx.x == 0) {
            for (int i = t; i < N_GRAPHS * HID; i += 1024) { gmax[i] = 0.f; gsum[i] = 0.f; }
            if (t < N_GRAPHS) gcnt[t] = 0.f;
        }
        if (t < 256) cnt[t] = 0;
        __syncthreads();
        int e0 = blockIdx.x * EPB;
        // pass 1: rank within bucket (1 LDS atomic/edge)
        for (int i = t; i < EPB; i += 1024) {
            unsigned int d = (unsigned int)dst[e0 + i];
            rnk[i] = (unsigned short)atomicAdd(&cnt[d >> 8], 1);
        }
        __syncthreads();
        if (t < 256) scn[t] = cnt[t];
        __syncthreads();
        for (int d2 = 1; d2 < 256; d2 <<= 1) {
            int u = 0;
            if (t < 256 && t >= d2) u = scn[t - d2];
            __syncthreads();
            if (t < 256) scn[t] += u;
            __syncthreads();
        }
        if (t < 256) lofs[t] = scn[t] - cnt[t];
        if (t < NBUCK) gbase[t] = t * BCAP + atomicAdd(&gcur[t], cnt[t]);
        __syncthreads();
        // pass 2: re-read (L2-hot), place into bucket-grouped LDS (no atomic)
        for (int i = t; i < EPB; i += 1024) {
            unsigned int d = (unsigned int)dst[e0 + i];
            unsigned int s = (unsigned int)srcv[e0 + i];
            ep2[lofs[d >> 8] + rnk[i]] = (d << 16) | s;
        }
        __syncthreads();
        // pass 3: coalesced global write
        for (int i = t; i < EPB; i += 1024) {
            unsigned int e = ep2[i];
            int bk = e >> 24;
            int gp = gbase[bk] + (i - lofs[bk]);
            if (gp < (bk + 1) * BCAP) padded[gp] = e;  // guard never fires
        }
    } else {
        float* sWrel  = (float*)smem;
        float* sWroot = sWrel + N_FEAT * HID;
        for (int i = t; i < N_FEAT * HID; i += 1024) { sWrel[i] = Wrel[i]; sWroot[i] = Wroot[i]; }
        __syncthreads();
        int idx = (blockIdx.x - 256) * 1024 + t;
        if (idx < N_NODES * HID) {
            int n = idx / HID, j = idx % HID;
            const float* xr = x + n * N_FEAT;
            float a0 = 0.f, a1 = bb[j];
            #pragma unroll
            for (int k = 0; k < N_FEAT; ++k) {
                float xv = xr[k];
                a0 = fmaf(xv, sWrel[k * HID + j], a0);
                a1 = fmaf(xv, sWroot[k * HID + j], a1);
            }
            y[(size_t)n * YSTR + j] = f2bf(a0);
            acc[idx] = a1;
        }
    }
}

// ================= K2: counting sort + perm + gather1 (2 lanes/node) + gemm2 ========

__global__ __launch_bounds__(1024) void k2_build_gather(
        const int* __restrict__ gcur, const unsigned int* __restrict__ padded,
        unsigned short* __restrict__ csr16, int* __restrict__ startg,
        int* __restrict__ cntg, unsigned short* __restrict__ permg,
        const unsigned short* __restrict__ y_in, const float* __restrict__ accp,
        const float* __restrict__ Wrel, const float* __restrict__ Wroot,
        const float* __restrict__ bb,
        unsigned short* __restrict__ y_out, float* __restrict__ acc_out) {
    __shared__ unsigned short eo[BCAP];          // 20 KB sorted src lists
    __shared__ char uni[20480];                  // rnk (sort) then rh (gather)
    __shared__ float sWrel[HID * HID], sWroot[HID * HID], sb[HID];
    __shared__ int cnt[256], scn[256], s_start[256], s_cnt[256];
    __shared__ unsigned short sperm[256];
    unsigned short* rnk = (unsigned short*)uni;
    float*          rh  = (float*)uni;
    int g = blockIdx.x, t = threadIdx.x;
    int base = g * BCAP;
    int m = min(gcur[g], BCAP);
    int n0 = g * 256;
    int nvalid = min(256, N_NODES - n0);
    for (int i = t; i < HID * HID; i += 1024) { sWrel[i] = Wrel[i]; sWroot[i] = Wroot[i]; }
    if (t < HID) sb[t] = bb[t];
    if (t < 256) cnt[t] = 0;
    __syncthreads();
    // rank within node
    for (int i = t; i < m; i += 1024) {
        int local = (padded[base + i] >> 16) & 255;
        rnk[i] = (unsigned short)atomicAdd(&cnt[local], 1);
    }
    __syncthreads();
    if (t < 256) { s_cnt[t] = cnt[t]; scn[t] = cnt[t]; }
    __syncthreads();
    for (int d = 1; d < 256; d <<= 1) {
        int u = 0;
        if (t < 256 && t >= d) u = scn[t - d];
        __syncthreads();
        if (t < 256) scn[t] += u;
        __syncthreads();
    }
    if (t < 256) {
        s_start[t] = scn[t] - s_cnt[t];
        if (t < nvalid) { startg[n0 + t] = base + s_start[t]; cntg[n0 + t] = s_cnt[t]; }
    }
    __syncthreads();
    // place (no atomic)
    for (int i = t; i < m; i += 1024) {
        unsigned int e = padded[base + i];
        int local = (e >> 16) & 255;
        eo[s_start[local] + rnk[i]] = (unsigned short)(e & 0xFFFFu);
    }
    __syncthreads();                              // rnk dead after here
    for (int i = t; i < m; i += 1024) csr16[base + i] = eo[i];
    // degree-descending perm by comparison rank
    if (t < 256) {
        int d = s_cnt[t], rank = 0;
        for (int j2 = 0; j2 < 256; ++j2) {
            int dj = s_cnt[j2];
            rank += (dj > d) || (dj == d && j2 < t);
        }
        sperm[rank] = (unsigned short)t;
    }
    __syncthreads();
    if (t < 256) permg[g * 256 + t] = sperm[t];
    // gather: 2 lanes per node, register accumulation, eo from LDS
    bool act = t < 512;
    int slot = t >> 1, half = t & 1;
    float a[HID];
    #pragma unroll
    for (int j = 0; j < HID; ++j) a[j] = 0.f;
    int nl = 0; bool ok = false; int a0 = 0, cn = 0;
    if (act) {
        nl = sperm[slot];
        ok = nl < nvalid;
        if (ok) { a0 = s_start[nl]; cn = s_cnt[nl]; }
    }
    if (ok) {
        #pragma unroll 2
        for (int k = half; k < cn; k += 2) addrow(y_in, eo[a0 + k], a);
        if (half == 0) {
            const float4* ar = (const float4*)(accp + (size_t)(n0 + nl) * HID);
            #pragma unroll
            for (int q = 0; q < 5; ++q) {
                float4 v = ar[q];
                a[q*4+0] += v.x; a[q*4+1] += v.y; a[q*4+2] += v.z; a[q*4+3] += v.w;
            }
        }
    }
    if (ok && half == 0) {
        #pragma unroll
        for (int q = 0; q < 5; ++q)
            *(float4*)&rh[nl * HID + q * 4] =
                make_float4(a[q*4], a[q*4+1], a[q*4+2], a[q*4+3]);
    }
    __syncthreads();
    if (ok && half == 1) {
        #pragma unroll
        for (int q = 0; q < 5; ++q) {
            float4 v = *(float4*)&rh[nl * HID + q * 4];
            v.x += a[q*4]; v.y += a[q*4+1]; v.z += a[q*4+2]; v.w += a[q*4+3];
            *(float4*)&rh[nl * HID + q * 4] = v;
        }
    }
    __syncthreads();
    // gemm2 from LDS
    for (int i = t; i < nvalid * 5; i += 1024) {
        int n = i / 5, j0 = (i % 5) * 4;
        float y0 = 0.f, y1 = 0.f, y2 = 0.f, y3 = 0.f;
        float c0 = sb[j0], c1 = sb[j0+1], c2 = sb[j0+2], c3 = sb[j0+3];
        #pragma unroll
        for (int k = 0; k < HID; ++k) {
            float h = fmaxf(rh[n * HID + k], 0.f);
            const float* wr = sWrel  + k * HID + j0;
            const float* wo = sWroot + k * HID + j0;
            y0 = fmaf(h, wr[0], y0); y1 = fmaf(h, wr[1], y1);
            y2 = fmaf(h, wr[2], y2); y3 = fmaf(h, wr[3], y3);
            c0 = fmaf(h, wo[0], c0); c1 = fmaf(h, wo[1], c1);
            c2 = fmaf(h, wo[2], c2); c3 = fmaf(h, wo[3], c3);
        }
        *(uint2*)(y_out + (size_t)(n0 + n) * YSTR + j0) = make_uint2(pk2(y0, y1), pk2(y2, y3));
        *(float4*)(acc_out + (size_t)(n0 + n) * HID + j0) = make_float4(c0, c1, c2, c3);
    }
}

// ================= K3: gather (4 lanes/node, global csr) + gemm3 ====================

__global__ __launch_bounds__(1024) void k3_gather_gemm(
        const int* __restrict__ startg, const int* __restrict__ cntg,
        const unsigned short* __restrict__ csr16, const unsigned short* __restrict__ permg,
        const unsigned short* __restrict__ y_in, const float* __restrict__ accp,
        const float* __restrict__ Wrel, const float* __restrict__ Wroot,
        const float* __restrict__ bb,
        unsigned short* __restrict__ y_out, float* __restrict__ acc_out) {
    __shared__ float rh[256 * HID];
    __shared__ float rh2[256 * HID];
    __shared__ float sWrel[HID * HID], sWroot[HID * HID], sb[HID];
    __shared__ unsigned short sperm[256];
    int g = blockIdx.x, t = threadIdx.x;
    int n0 = g * 256;
    int nvalid = min(256, N_NODES - n0);
    for (int i = t; i < HID * HID; i += 1024) { sWrel[i] = Wrel[i]; sWroot[i] = Wroot[i]; }
    if (t < HID) sb[t] = bb[t];
    if (t < 256) sperm[t] = permg[g * 256 + t];
    __syncthreads();
    int slot = t >> 2, q = t & 3;
    int nl = sperm[slot];
    bool ok = nl < nvalid;
    float a[HID];
    #pragma unroll
    for (int j = 0; j < HID; ++j) a[j] = 0.f;
    if (ok) {
        int node = n0 + nl;
        int a0 = startg[node], cn = cntg[node];
        #pragma unroll 2
        for (int k = q; k < cn; k += 4) addrow(y_in, csr16[a0 + k], a);
        if (q == 0) {
            const float4* ar = (const float4*)(accp + (size_t)node * HID);
            #pragma unroll
            for (int qq = 0; qq < 5; ++qq) {
                float4 v = ar[qq];
                a[qq*4+0] += v.x; a[qq*4+1] += v.y; a[qq*4+2] += v.z; a[qq*4+3] += v.w;
            }
        }
    }
    if (ok && (q == 0 || q == 2)) {
        float* dstp = (q == 0) ? rh : rh2;
        #pragma unroll
        for (int qq = 0; qq < 5; ++qq)
            *(float4*)&dstp[nl * HID + qq * 4] =
                make_float4(a[qq*4], a[qq*4+1], a[qq*4+2], a[qq*4+3]);
    }
    __syncthreads();
    if (ok && (q == 1 || q == 3)) {
        float* dstp = (q == 1) ? rh : rh2;
        #pragma unroll
        for (int qq = 0; qq < 5; ++qq) {
            float4 v = *(float4*)&dstp[nl * HID + qq * 4];
            v.x += a[qq*4]; v.y += a[qq*4+1]; v.z += a[qq*4+2]; v.w += a[qq*4+3];
            *(float4*)&dstp[nl * HID + qq * 4] = v;
        }
    }
    __syncthreads();
    for (int i = t; i < nvalid * 5; i += 1024) {
        int n = i / 5, j0 = (i % 5) * 4;
        float y0 = 0.f, y1 = 0.f, y2 = 0.f, y3 = 0.f;
        float c0 = sb[j0], c1 = sb[j0+1], c2 = sb[j0+2], c3 = sb[j0+3];
        #pragma unroll
        for (int k = 0; k < HID; ++k) {
            float h = fmaxf(rh[n * HID + k] + rh2[n * HID + k], 0.f);
            const float* wr = sWrel  + k * HID + j0;
            const float* wo = sWroot + k * HID + j0;
            y0 = fmaf(h, wr[0], y0); y1 = fmaf(h, wr[1], y1);
            y2 = fmaf(h, wr[2], y2); y3 = fmaf(h, wr[3], y3);
            c0 = fmaf(h, wo[0], c0); c1 = fmaf(h, wo[1], c1);
            c2 = fmaf(h, wo[2], c2); c3 = fmaf(h, wo[3], c3);
        }
        *(uint2*)(y_out + (size_t)(n0 + n) * YSTR + j0) = make_uint2(pk2(y0, y1), pk2(y2, y3));
        *(float4*)(acc_out + (size_t)(n0 + n) * HID + j0) = make_float4(c0, c1, c2, c3);
    }
}

// ================= K4: gather (4 lanes/node) + pooling + last-block final linear ====

__global__ __launch_bounds__(1024) void k4_gather_pool(
        const int* __restrict__ startg, const int* __restrict__ cntg,
        const unsigned short* __restrict__ csr16, const unsigned short* __restrict__ permg,
        const unsigned short* __restrict__ y_in, const float* __restrict__ accp,
        const int* __restrict__ batch,
        float* __restrict__ gmax, float* __restrict__ gsum, float* __restrict__ gcnt,
        int* __restrict__ done, const float* __restrict__ Wlin,
        const float* __restrict__ blin, float* __restrict__ out) {
    __shared__ float rh[256 * HID];
    __shared__ float rh2[256 * HID];
    __shared__ float redm[51 * HID], reds[51 * HID];
    __shared__ unsigned short sperm[256];
    __shared__ int sbatch[256];
    __shared__ int seglo[16], seghi[16];
    __shared__ int lastFlag;
    int g = blockIdx.x, t = threadIdx.x;
    int n0 = g * 256;
    int nvalid = min(256, N_NODES - n0);
    if (t < 256) sperm[t] = permg[g * 256 + t];
    if (t < nvalid) sbatch[t] = batch[n0 + t];
    __syncthreads();
    int slot = t >> 2, q = t & 3;
    int nl = sperm[slot];
    bool ok = nl < nvalid;
    float a[HID];
    #pragma unroll
    for (int j = 0; j < HID; ++j) a[j] = 0.f;
    if (ok) {
        int node = n0 + nl;
        int a0 = startg[node], cn = cntg[node];
        #pragma unroll 2
        for (int k = q; k < cn; k += 4) addrow(y_in, csr16[a0 + k], a);
        if (q == 0) {
            const float4* ar = (const float4*)(accp + (size_t)node * HID);
            #pragma unroll
            for (int qq = 0; qq < 5; ++qq) {
                float4 v = ar[qq];
                a[qq*4+0] += v.x; a[qq*4+1] += v.y; a[qq*4+2] += v.z; a[qq*4+3] += v.w;
            }
        }
    }
    if (ok && (q == 0 || q == 2)) {
        float* dstp = (q == 0) ? rh : rh2;
        #pragma unroll
        for (int qq = 0; qq < 5; ++qq)
            *(float4*)&dstp[nl * HID + qq * 4] =
                make_float4(a[qq*4], a[qq*4+1], a[qq*4+2], a[qq*4+3]);
    }
    __syncthreads();
    if (ok && (q == 1 || q == 3)) {
        float* dstp = (q == 1) ? rh : rh2;
        #pragma unroll
        for (int qq = 0; qq < 5; ++qq) {
            float4 v = *(float4*)&dstp[nl * HID + qq * 4];
            v.x += a[qq*4]; v.y += a[qq*4+1]; v.z += a[qq*4+2]; v.w += a[qq*4+3];
            *(float4*)&dstp[nl * HID + qq * 4] = v;
        }
    }
    __syncthreads();
    // segmented max/mean pooling (batch sorted)
    int g0 = sbatch[0];
    int span = sbatch[nvalid - 1] - g0 + 1;
    if (t < nvalid) {
        int bi = sbatch[t] - g0;
        if (bi < 16) {
            if (t == 0 || sbatch[t - 1] != sbatch[t]) seglo[bi] = t;
            if (t == nvalid - 1 || sbatch[t + 1] != sbatch[t]) seghi[bi] = t + 1;
        }
    }
    __syncthreads();
    if (span > 16) span = 16;
    for (int li = 0; li < span; ++li) {
        int lo = seglo[li], hi = seghi[li];
        int r = t / HID, j = t % HID;
        if (r < 51) {
            float mx = 0.f, sm = 0.f;
            for (int n = lo + r; n < hi; n += 51) {
                float v = fmaxf(rh[n * HID + j] + rh2[n * HID + j], 0.f);
                mx = fmaxf(mx, v); sm += v;
            }
            redm[r * HID + j] = mx; reds[r * HID + j] = sm;
        }
        __syncthreads();
        if (t < HID) {
            float mm = 0.f, ss = 0.f;
            #pragma unroll 17
            for (int r2 = 0; r2 < 51; ++r2) {
                mm = fmaxf(mm, redm[r2 * HID + t]);
                ss += reds[r2 * HID + t];
            }
            atomicMax((int*)&gmax[(g0 + li) * HID + t], __float_as_int(mm));
            atomicAdd(&gsum[(g0 + li) * HID + t], ss);
        }
        if (t == HID) atomicAdd(&gcnt[g0 + li], (float)(hi - lo));
        __syncthreads();
    }
    // last block: final linear
    if (t == 0) {
        __threadfence();
        lastFlag = (atomicAdd(done, 1) == NBUCK - 1);
    }
    __syncthreads();
    if (!lastFlag) return;
    __threadfence();
    float* sW = redm;
    for (int i = t; i < 2 * HID * OUT_DIM; i += 1024) sW[i] = Wlin[i];
    __syncthreads();
    if (t < N_GRAPHS * OUT_DIM) {
        int gg = t / OUT_DIM, o = t % OUT_DIM;
        float c = fmaxf(gcnt[gg], 1.0f);
        float av = blin[o];
        #pragma unroll
        for (int j = 0; j < HID; ++j) {
            av = fmaf(gmax[gg * HID + j], sW[j * OUT_DIM + o], av);
            av = fmaf(gsum[gg * HID + j] / c, sW[(HID + j) * OUT_DIM + o], av);
        }
        out[t] = av;
    }
}

extern "C" void kernel_launch(void* const* d_in, const int* in_sizes, int n_in,
                              void* d_out, int out_size, void* d_ws, size_t ws_size,
                              hipStream_t stream) {
    const float* x      = (const float*)d_in[0];
    const int*   ei     = (const int*)  d_in[1];
    const int*   batch  = (const int*)  d_in[2];
    const float* Wrel1  = (const float*)d_in[3];
    const float* Wroot1 = (const float*)d_in[4];
    const float* b1     = (const float*)d_in[5];
    const float* Wrel2  = (const float*)d_in[6];
    const float* Wroot2 = (const float*)d_in[7];
    const float* b2     = (const float*)d_in[8];
    const float* Wrel3  = (const float*)d_in[9];
    const float* Wroot3 = (const float*)d_in[10];
    const float* b3     = (const float*)d_in[11];
    const float* Wlin   = (const float*)d_in[12];
    const float* blin   = (const float*)d_in[13];
    float* out = (float*)d_out;

    char* ws = (char*)d_ws;
    const size_t YB = (size_t)N_NODES * YSTR * 2;                   // 3,200,000 (bf16)
    const size_t AB = (size_t)N_NODES * HID * 4;                    // 4,000,000
    const size_t PB = (size_t)NBUCK * BCAP * 4;                     // 8,028,160
    const size_t CB = (size_t)NBUCK * BCAP * 2;                     // 4,014,080
    const size_t NP = (size_t)NBUCK * 256;                          // 50,176
    unsigned short* yA     = (unsigned short*)(ws);
    unsigned short* yB     = (unsigned short*)(ws + YB);
    float*          accA   = (float*)(ws + 2 * YB);
    float*          accB   = (float*)(ws + 2 * YB + AB);
    unsigned int*   padded = (unsigned int*)(ws + 2 * YB + 2 * AB);
    unsigned short* csr16  = (unsigned short*)(ws + 2 * YB + 2 * AB + PB);
    int*            startg = (int*)(ws + 2 * YB + 2 * AB + PB + CB);
    int*            cntg   = startg + NP;
    unsigned short* permg  = (unsigned short*)(cntg + NP);
    int*            gcur   = (int*)((char*)permg + NP * 2);
    int*            done   = gcur + NBUCK;
    float*          gmax   = (float*)(done + 4);
    float*          gsum   = gmax + N_GRAPHS * HID;
    float*          gcnt   = gsum + N_GRAPHS * HID;

    const int* src = ei;
    const int* dst = ei + N_EDGES;

    hipMemsetAsync(gcur, 0, (NBUCK + 1) * sizeof(int), stream);
    // K1: scatter (blocks 0-255, rank-trick + coalesced write) || gemm50 -> bf16 y
    k1_scatter_gemm<<<256 + GEMMB, 1024, 0, stream>>>(dst, src, gcur, padded,
                                                      x, Wrel1, Wroot1, b1, yA, accA,
                                                      gmax, gsum, gcnt);
    // K2: counting sort + perm + L1 gather (2 lanes/node, LDS src) + gemm2
    k2_build_gather<<<NBUCK, 1024, 0, stream>>>(gcur, padded, csr16, startg, cntg, permg,
                                                yA, accA, Wrel2, Wroot2, b2, yB, accB);
    // K3: L2 gather (4 lanes/node) + gemm3
    k3_gather_gemm<<<NBUCK, 1024, 0, stream>>>(startg, cntg, csr16, permg,
                                               yB, accB, Wrel3, Wroot3, b3, yA, accA);
    // K4: L3 gather + pooling + fused final linear
    k4_gather_pool<<<NBUCK, 1024, 0, stream>>>(startg, cntg, csr16, permg,
                                               yA, accA, batch, gmax, gsum, gcnt,
                                               done, Wlin, blin, out);
}